// Round 6
// baseline (5501.453 us; speedup 1.0000x reference)
//
#include <hip/hip_runtime.h>
#include <math.h>

#define TT 512
#define BB 64
#define DIN 256
#define HH 512
#define DOUT 256

// A tiles: A_HI / A_LO, each 16 rows x 768 f16; rows 0-7 = batches 0-7,
// rows 8-15 zeroed (MFMA ballast — D rows 8-15 are never read).
#define RSU 388          // row stride in u32 (384 data + 4 pad, 16B-aligned rows)
#define RSH 776          // row stride in f16
#define PST 68           // p_l row stride in f32

// LDS layout (u32 units)
#define A_HI_OFF 0
#define A_LO_OFF 6208    // 16*388
#define P_OFF    12416   // 16 rows x PST = 1088
#define B_OFF    13504   // 64 biases
#define C_OFF    13568   // 128 cell states
#define HST_HI   13696   // 64 u32 (128 u16) h-hi stage
#define HST_LO   13760   // 64 u32 h-lo stage
#define SMEM_U32 13824
#define SMEM_BYTES (SMEM_U32*4)

#define FCS 516          // fc LDS stride

typedef _Float16 f16x8 __attribute__((ext_vector_type(8)));
typedef float    f32x4 __attribute__((ext_vector_type(4)));
typedef unsigned u32x4 __attribute__((ext_vector_type(4)));

union H16 { _Float16 f; unsigned short u; };
__device__ __forceinline__ unsigned short f16bits(_Float16 h) { H16 t; t.f = h; return t.u; }

// split x,y into f16 hi + scaled-lo (lo = (x-hi)*2048 stays in f16 normal range)
__device__ __forceinline__ void pack2(float x, float y, unsigned& hi, unsigned& lo) {
    _Float16 hx = (_Float16)x, hy = (_Float16)y;
    _Float16 lx = (_Float16)((x - (float)hx) * 2048.0f);
    _Float16 ly = (_Float16)((y - (float)hy) * 2048.0f);
    hi = (unsigned)f16bits(hx) | ((unsigned)f16bits(hy) << 16);
    lo = (unsigned)f16bits(lx) | ((unsigned)f16bits(ly) << 16);
}

// coherent (LLC) 16B load/store — the ONLY exchange path. sc0 sc1 is the
// verified-correct coherence point (R1/R2 passed with exactly this);
// sc0-only "L2 fast path" was removed: its L1/L2 semantics are unproven and
// it reproducibly returned 4-step-stale tag-matching data (R3-R5 failures).
__device__ __forceinline__ u32x4 ld16_cohere(const void* p) {
    u32x4 v;
    asm volatile("global_load_dwordx4 %0, %1, off sc0 sc1"
                 : "=&v"(v) : "v"(p) : "memory");
    return v;
}
__device__ __forceinline__ void st16_cohere(void* p, u32x4 v) {
    asm volatile("global_store_dwordx4 %0, %1, off sc0 sc1"
                 :: "v"(p), "v"(v) : "memory");
}

// tag check: every u16 LSB of the 16B vector must equal `par`.
__device__ __forceinline__ bool tag_ok(u32x4 v, unsigned par) {
    unsigned a = v[0] & v[1] & v[2] & v[3];
    unsigned o = v[0] | v[1] | v[2] | v[3];
    unsigned x = par ? ~a : o;
    return (x & 0x00010001u) == 0u;
}

// ---------------- W fragments: fp32 global -> f16 hi/lo REGISTERS ----------------
// Wave (ct,kh) covers gate-cols [ct*32, ct*32+32) (2 subtiles of 16) and k-slices
// kh*12..kh*12+12. Lane (m,q): B-frag col = base+m, k = slice*32 + q*8.
__device__ __forceinline__ void load_w_regs(const float* __restrict__ Whh,
                                            const float* __restrict__ Wih,
                                            int u0, int ct, int kh, int m, int q,
                                            f16x8 (&whi)[2][12], f16x8 (&wlo)[2][12]) {
    #pragma unroll
    for (int t = 0; t < 2; ++t) {
        const int col = ct*32 + t*16 + m;              // 0..63 gate-major
        const int C   = (col >> 4)*HH + u0 + (col & 15);
        const float* rowH = Whh + (size_t)C*HH;
        const float* rowI = Wih + (size_t)C*DIN;
        #pragma unroll
        for (int j = 0; j < 12; ++j) {
            const int ks = kh*12 + j;                  // 0..23
            const float* src = (ks < 16) ? (rowH + ks*32 + q*8)
                                         : (rowI + (ks - 16)*32 + q*8);
            float4 a = ((const float4*)src)[0];
            float4 b = ((const float4*)src)[1];
            f16x8 h8, l8; _Float16 t16;
            t16=(_Float16)a.x; h8[0]=t16; l8[0]=(_Float16)((a.x-(float)t16)*2048.0f);
            t16=(_Float16)a.y; h8[1]=t16; l8[1]=(_Float16)((a.y-(float)t16)*2048.0f);
            t16=(_Float16)a.z; h8[2]=t16; l8[2]=(_Float16)((a.z-(float)t16)*2048.0f);
            t16=(_Float16)a.w; h8[3]=t16; l8[3]=(_Float16)((a.w-(float)t16)*2048.0f);
            t16=(_Float16)b.x; h8[4]=t16; l8[4]=(_Float16)((b.x-(float)t16)*2048.0f);
            t16=(_Float16)b.y; h8[5]=t16; l8[5]=(_Float16)((b.y-(float)t16)*2048.0f);
            t16=(_Float16)b.z; h8[6]=t16; l8[6]=(_Float16)((b.z-(float)t16)*2048.0f);
            t16=(_Float16)b.w; h8[7]=t16; l8[7]=(_Float16)((b.w-(float)t16)*2048.0f);
            whi[t][j] = h8; wlo[t][j] = l8;
        }
    }
}

// ---------------- x staging: fp32 global -> A_HI/A_LO rows 0-7, k in [512,768) ----------------
__device__ __forceinline__ void stage_x_f16(unsigned* __restrict__ sm32,
                                            const float* __restrict__ src, int tid) {
    for (int r = 0; r < 2; ++r) {
        int idx4 = tid + 256*r;          // 512 float4 = 8 rows x 64
        int b = idx4 >> 6, j4 = idx4 & 63;
        float4 v = ((const float4*)(src + (size_t)b*DIN))[j4];
        unsigned h0, l0, h1, l1;
        pack2(v.x, v.y, h0, l0);
        pack2(v.z, v.w, h1, l1);
        int o = b*RSU + 256 + 2*j4;
        sm32[A_HI_OFF + o]     = h0;
        sm32[A_HI_OFF + o + 1] = h1;
        sm32[A_LO_OFF + o]     = l0;
        sm32[A_LO_OFF + o + 1] = l1;
    }
}

__device__ __forceinline__ void stage_x_zero_f16(unsigned* __restrict__ sm32, int tid) {
    for (int r = 0; r < 2; ++r) {
        int idx = tid + 256*r;           // 512: 8 rows x 64
        int row = idx >> 6, j = idx & 63;
        int o = row*RSU + 256 + 2*j;
        sm32[A_HI_OFF + o]     = 0u;
        sm32[A_HI_OFF + o + 1] = 0u;
        sm32[A_LO_OFF + o]     = 0u;
        sm32[A_LO_OFF + o + 1] = 0u;
    }
}

// ---------------- persistent LSTM kernel (8x32x16 geometry, pure-LLC exchange) ----------------
// BISECT BUILD (single variable vs R5): the sc0-only "L2 fast path",
// handshake, probe, and dual-store are DELETED. Exchange protocol is exactly
// the R1/R2-proven one (tag-in-data, sc0sc1 publish + sc0sc1 poll). Geometry
// is the new one: 8 groups x 8 batches, 32 producers x 16 units.
__global__ __launch_bounds__(256, 1)
void lstm_persist(const float* __restrict__ x, const float* __restrict__ target,
                  const float* __restrict__ h0, const float* __restrict__ c0,
                  const float* __restrict__ eWih, const float* __restrict__ eWhh,
                  const float* __restrict__ eb,
                  const float* __restrict__ dWih, const float* __restrict__ dWhh,
                  const float* __restrict__ db,
                  float* __restrict__ hs,
                  unsigned short* __restrict__ hbh,   // [2][64][512] f16-hi
                  unsigned short* __restrict__ hbl)   // [2][64][512] f16-lo
{
    extern __shared__ unsigned sm32[];
    float* p_l = (float*)(sm32 + P_OFF);
    float* b_l = (float*)(sm32 + B_OFF);
    float* c_l = (float*)(sm32 + C_OFF);
    unsigned* hst_hi = sm32 + HST_HI;
    unsigned* hst_lo = sm32 + HST_LO;

    const int tid = (int)threadIdx.x;
    const int g   = (int)(blockIdx.x & 7);     // batch group 0..7
    const int ij  = (int)(blockIdx.x >> 3);    // producer id 0..31
    const int b0  = g * 8;
    const int u0  = ij * 16;

    // ---- initial staging ----
    if (tid < 128) {
        int b = tid >> 4, u = tid & 15;
        c_l[tid] = c0[(size_t)(b0 + b)*HH + u0 + u];
    }
    if (tid < 64) b_l[tid] = eb[(tid >> 4)*HH + u0 + (tid & 15)];
    // zero A rows 8-15 (never re-written; D rows 8-15 are ignored ballast)
    for (int i = tid; i < 8*RSU; i += 256) {
        sm32[A_HI_OFF + 8*RSU + i] = 0u;
        sm32[A_LO_OFF + 8*RSU + i] = 0u;
    }
    stage_x_f16(sm32, x + (size_t)b0*DIN, tid);     // x for s=0
    for (int r = 0; r < 4; ++r) {                    // h_{-1}=h0 -> A_HI/A_LO rows 0-7
        int idx4 = tid + 256*r;          // 1024 float4 = 8 rows x 128
        int b = idx4 >> 7, j4 = idx4 & 127;
        float4 v = ((const float4*)(h0 + (size_t)(b0 + b)*HH))[j4];
        unsigned h0p, l0p, h1p, l1p;
        pack2(v.x, v.y, h0p, l0p);
        pack2(v.z, v.w, h1p, l1p);
        int o = b*RSU + 2*j4;
        sm32[A_HI_OFF + o]     = h0p;
        sm32[A_HI_OFF + o + 1] = h1p;
        sm32[A_LO_OFF + o]     = l0p;
        sm32[A_LO_OFF + o + 1] = l1p;
    }
    __syncthreads();

    const int lane = tid & 63;
    const int wid  = tid >> 6;
    const int m    = lane & 15;        // A row sel / B col sel
    const int q    = lane >> 4;        // quad
    const int ct   = wid & 1;          // col-half (32 of 64 gate-cols)
    const int kh   = wid >> 1;         // k-half (12 of 24 slices)

    const _Float16* aH = (const _Float16*)(sm32 + A_HI_OFF);
    const _Float16* aL = (const _Float16*)(sm32 + A_LO_OFF);
    const int abase = m*RSH + q*8 + (kh*12)*32;

    f16x8 whi[2][12], wlo[2][12];
    load_w_regs(eWhh, eWih, u0, ct, kh, m, q, whi, wlo);

    for (int s = 0; s < 1024; ++s) {
        // ---- 1. MFMA GEMM (R2 structure): 3 products per col-subtile ----
        f32x4 hh0 = {0.f,0.f,0.f,0.f}, hl0 = {0.f,0.f,0.f,0.f}, lh0 = {0.f,0.f,0.f,0.f};
        f32x4 hh1 = {0.f,0.f,0.f,0.f}, hl1 = {0.f,0.f,0.f,0.f}, lh1 = {0.f,0.f,0.f,0.f};
        #pragma unroll
        for (int j = 0; j < 12; ++j) {
            f16x8 ah = *(const f16x8*)(aH + abase + j*32);
            f16x8 al = *(const f16x8*)(aL + abase + j*32);
            hh0 = __builtin_amdgcn_mfma_f32_16x16x32_f16(ah, whi[0][j], hh0, 0, 0, 0);
            hl0 = __builtin_amdgcn_mfma_f32_16x16x32_f16(ah, wlo[0][j], hl0, 0, 0, 0);
            lh0 = __builtin_amdgcn_mfma_f32_16x16x32_f16(al, whi[0][j], lh0, 0, 0, 0);
            hh1 = __builtin_amdgcn_mfma_f32_16x16x32_f16(ah, whi[1][j], hh1, 0, 0, 0);
            hl1 = __builtin_amdgcn_mfma_f32_16x16x32_f16(ah, wlo[1][j], hl1, 0, 0, 0);
            lh1 = __builtin_amdgcn_mfma_f32_16x16x32_f16(al, whi[1][j], lh1, 0, 0, 0);
        }
        if (q < 2) {
            // D rows 0-7 (= batches 0-7): C = Chh + (Chl + Clh)/2048
            const float sc = 1.0f/2048.0f;
            float* pb = p_l + (kh*8 + q*4)*PST + ct*32 + m;
            #pragma unroll
            for (int i = 0; i < 4; ++i) {
                pb[i*PST]      = hh0[i] + (hl0[i] + lh0[i])*sc;
                pb[i*PST + 16] = hh1[i] + (hl1[i] + lh1[i])*sc;
            }
        }
        __syncthreads();

        const unsigned par = (unsigned)(((s + 1) >> 1) & 1);   // step tag bit

        // ---- 2. elementwise LSTM update -> LDS h-stage (tagged split-f16) ----
        float hval = 0.f;
        if (tid < 128) {
            const int b = tid >> 4, u = tid & 15;
            float gi = b_l[u], gf = b_l[16+u], gg = b_l[32+u], go = b_l[48+u];
            #pragma unroll
            for (int ps = 0; ps < 2; ++ps) {
                const float* pp = p_l + (ps*8 + b)*PST;
                gi += pp[u]; gf += pp[16+u]; gg += pp[32+u]; go += pp[48+u];
            }
            float ii = 1.f/(1.f + expf(-gi));
            float ff = 1.f/(1.f + expf(-gf));
            float g2 = tanhf(gg);
            float oo = 1.f/(1.f + expf(-go));
            float c  = ff*c_l[tid] + ii*g2;
            c_l[tid] = c;
            hval = oo*tanhf(c);
            _Float16 hh = (_Float16)hval;
            unsigned uh = ((unsigned)f16bits(hh) & 0xFFFEu) | par;
            H16 t16; t16.u = (unsigned short)uh;
            _Float16 hl = (_Float16)((hval - (float)t16.f) * 2048.0f);
            unsigned ul = ((unsigned)f16bits(hl) & 0xFFFEu) | par;
            ((unsigned short*)hst_hi)[tid] = (unsigned short)uh;   // tid = b*16+u
            ((unsigned short*)hst_lo)[tid] = (unsigned short)ul;
        }
        __syncthreads();

        // ---- 3. publish: wave0 fires 32 coherent 16B stores — no ack wait ----
        if (tid < 32) {
            // order prior-step publishes before this one (waits on ~1-step-old
            // traffic only -> essentially free); guarantees period-4 tag safety.
            asm volatile("s_waitcnt vmcnt(0)" ::: "memory");
            const int idx = tid & 15, isLo = tid >> 4;
            const int b = idx >> 1, h16 = idx & 1;
            u32x4 v = *(const u32x4*)((isLo ? hst_lo : hst_hi) + b*8 + h16*4);
            unsigned short* base = (isLo ? hbl : hbh)
                + ((size_t)((s & 1) ^ 1)*BB + b0 + b)*HH + u0 + h16*8;
            st16_cohere(base, v);
        }

        // ---- 4. off-critical-path tail ----
        if (s >= 512 && tid < 128) {
            int b = tid >> 4, u = tid & 15;
            hs[((size_t)(s - 512)*BB + (b0 + b))*HH + (u0 + u)] = hval;
        }
        if (s == 511) {
            load_w_regs(dWhh, dWih, u0, ct, kh, m, q, whi, wlo);   // decoder W
            if (tid < 64) b_l[tid] = db[(tid >> 4)*HH + u0 + (tid & 15)];
        }
        {
            int ns = s + 1;
            if (ns < 1024) {
                if (ns == 512)       stage_x_zero_f16(sm32, tid);
                else if (ns < 512)   stage_x_f16(sm32, x + ((size_t)ns*BB + b0)*DIN, tid);
                else                 stage_x_f16(sm32, target + ((size_t)(ns - 513)*BB + b0)*DOUT, tid);
            }
        }

        // ---- 5. gather h_s: poll the data itself (tag in every u16 LSB) ----
        if (s < 1023) {
            const int slot = (s + 1) & 1;
            const u32x4* SH = (const u32x4*)(hbh + (size_t)slot*BB*HH + (size_t)b0*HH);
            const u32x4* SL = (const u32x4*)(hbl + (size_t)slot*BB*HH + (size_t)b0*HH);
            u32x4 v0 = {0,0,0,0}, v1 = {0,0,0,0}, v2 = {0,0,0,0}, v3 = {0,0,0,0};
            unsigned pend = 0xFu; int tries = 0;
            do {
                if (pend & 1u) v0 = ld16_cohere(SH + tid);
                if (pend & 2u) v1 = ld16_cohere(SH + tid + 256);
                if (pend & 4u) v2 = ld16_cohere(SL + tid);
                if (pend & 8u) v3 = ld16_cohere(SL + tid + 256);
                asm volatile("s_waitcnt vmcnt(0)"
                             : "+v"(v0), "+v"(v1), "+v"(v2), "+v"(v3) :: "memory");
                if (tag_ok(v0, par)) pend &= ~1u;
                if (tag_ok(v1, par)) pend &= ~2u;
                if (tag_ok(v2, par)) pend &= ~4u;
                if (tag_ok(v3, par)) pend &= ~8u;
                ++tries;
                if (pend && tries > 4) __builtin_amdgcn_s_sleep(1);
            } while (pend);
            // scatter: hi -> A_HI rows 0-7, lo -> A_LO rows 0-7 (k in [0,512))
            const int j = tid & 63, r0 = tid >> 6;
            *(u32x4*)(sm32 + A_HI_OFF + (r0    )*RSU + j*4) = v0;
            *(u32x4*)(sm32 + A_HI_OFF + (r0 + 4)*RSU + j*4) = v1;
            *(u32x4*)(sm32 + A_LO_OFF + (r0    )*RSU + j*4) = v2;
            *(u32x4*)(sm32 + A_LO_OFF + (r0 + 4)*RSU + j*4) = v3;
        }
        __syncthreads();   // A (h+x) visible before next MFMA
    }
}

// ---------------- FC (logits) kernel ----------------
__global__ __launch_bounds__(256, 1)
void fc_kernel(const float* __restrict__ hs, const float* __restrict__ W,
               const float* __restrict__ bias, float* __restrict__ out)
{
    extern __shared__ float sm[];
    float* hs_l = sm;              // 16 x FCS
    float* w_l  = sm + 16*FCS;     // 32 x FCS

    const int tid = (int)threadIdx.x;
    const int rb = (int)(blockIdx.x >> 3);
    const int cb = (int)(blockIdx.x & 7);

    for (int r = 0; r < 8; ++r) {
        int id = tid + 256*r;
        int b = id >> 7, j = id & 127;
        float4 v = ((const float4*)(hs + (size_t)(rb*16 + b)*HH))[j];
        *(float4*)(hs_l + b*FCS + 4*j) = v;
    }
    for (int r = 0; r < 16; ++r) {
        int id = tid + 256*r;
        int c = id >> 7, j = id & 127;
        float4 v = ((const float4*)(W + (size_t)(cb*32 + c)*HH))[j];
        *(float4*)(w_l + c*FCS + 4*j) = v;
    }
    __syncthreads();

    const int kc = tid & 7, bt = (tid >> 3) & 3, ct = tid >> 5;
    float acc[4][4] = {};
    const float* ap = hs_l + (bt*4)*FCS + 4*kc;
    const float* wp = w_l  + (ct*4)*FCS + 4*kc;
    #pragma unroll 4
    for (int i = 0; i < 16; ++i) {
        float4 av[4], wv[4];
        #pragma unroll
        for (int q = 0; q < 4; ++q) av[q] = *(const float4*)(ap + q*FCS + 32*i);
        #pragma unroll
        for (int q = 0; q < 4; ++q) wv[q] = *(const float4*)(wp + q*FCS + 32*i);
        #pragma unroll
        for (int b2 = 0; b2 < 4; ++b2)
            #pragma unroll
            for (int c2 = 0; c2 < 4; ++c2)
                acc[b2][c2] += av[b2].x*wv[c2].x + av[b2].y*wv[c2].y
                             + av[b2].z*wv[c2].z + av[b2].w*wv[c2].w;
    }
    #pragma unroll
    for (int b2 = 0; b2 < 4; ++b2)
        #pragma unroll
        for (int c2 = 0; c2 < 4; ++c2) {
            float v = acc[b2][c2];
            v += __shfl_xor(v, 1, 64);
            v += __shfl_xor(v, 2, 64);
            v += __shfl_xor(v, 4, 64);
            acc[b2][c2] = v;
        }
    if (kc == 0) {
        #pragma unroll
        for (int b2 = 0; b2 < 4; ++b2)
            #pragma unroll
            for (int c2 = 0; c2 < 4; ++c2) {
                int row = rb*16 + bt*4 + b2;
                int col = cb*32 + ct*4 + c2;
                out[(size_t)row*DOUT + col] = acc[b2][c2] + bias[col];
            }
    }
}

// ---------------- in-place softmax over last dim (256) ----------------
__global__ __launch_bounds__(256, 1)
void softmax_kernel(float* __restrict__ out)
{
    int row  = (int)blockIdx.x * 4 + ((int)threadIdx.x >> 6);
    int lane = (int)threadIdx.x & 63;
    float4 v = ((const float4*)(out + (size_t)row*DOUT))[lane];
    float m = fmaxf(fmaxf(v.x, v.y), fmaxf(v.z, v.w));
    #pragma unroll
    for (int d = 1; d < 64; d <<= 1) m = fmaxf(m, __shfl_xor(m, d, 64));
    float ex = expf(v.x - m), ey = expf(v.y - m), ez = expf(v.z - m), ew = expf(v.w - m);
    float ssum = ex + ey + ez + ew;
    #pragma unroll
    for (int d = 1; d < 64; d <<= 1) ssum += __shfl_xor(ssum, d, 64);
    float inv = 1.f / ssum;
    float4 o = make_float4(ex*inv, ey*inv, ez*inv, ew*inv);
    ((float4*)(out + (size_t)row*DOUT))[lane] = o;
}

// ---------------- exchange-buffer tag init (ws poisoned 0xAA before every call) ----------------
// slot0 first read at s=1 expects tag 1 -> init LSBs to 0.
// slot1 first read at s=0 expects tag 0 -> init LSBs to 1.
// sc0sc1 stores: init state lives at the LLC, where all polls go.
__global__ void init_kernel(unsigned* __restrict__ hbh32, unsigned* __restrict__ hbl32)
{
    int i = (int)blockIdx.x * 256 + (int)threadIdx.x;    // 0..16383
    unsigned* base = (i < 8192) ? hbh32 : hbl32;
    int j = (i & 8191) * 4;                              // u32 offset 0..32764
    unsigned val = (j < 16384) ? 0u : 0x00010001u;       // slot0 : slot1
    u32x4 v = {val, val, val, val};
    st16_cohere(base + j, v);
}

// ---------------- launch ----------------
extern "C" void kernel_launch(void* const* d_in, const int* in_sizes, int n_in,
                              void* d_out, int out_size, void* d_ws, size_t ws_size,
                              hipStream_t stream) {
    (void)in_sizes; (void)n_in; (void)out_size; (void)ws_size;
    const float* x      = (const float*)d_in[0];
    const float* target = (const float*)d_in[1];
    const float* h0     = (const float*)d_in[2];
    const float* c0     = (const float*)d_in[3];
    const float* eWih   = (const float*)d_in[4];
    const float* eWhh   = (const float*)d_in[5];
    const float* eb     = (const float*)d_in[6];
    const float* dWih   = (const float*)d_in[7];
    const float* dWhh   = (const float*)d_in[8];
    const float* db     = (const float*)d_in[9];
    const float* fcW    = (const float*)d_in[10];
    const float* fcb    = (const float*)d_in[11];
    float* out = (float*)d_out;

    float* hs = (float*)d_ws + 1024;                    // [T*B*H] decoder hidden
    unsigned short* hbh = (unsigned short*)(hs + (size_t)TT*BB*HH);  // [2][64][512] hi
    unsigned short* hbl = hbh + (size_t)2*BB*HH;                     // [2][64][512] lo

    init_kernel<<<dim3(64), dim3(256), 0, stream>>>((unsigned*)hbh, (unsigned*)hbl);

    lstm_persist<<<dim3(256), dim3(256), SMEM_BYTES, stream>>>(
        x, target, h0, c0, eWih, eWhh, eb, dWih, dWhh, db, hs, hbh, hbl);

    size_t lds_fc = (size_t)(48*FCS) * sizeof(float);   // ~99 KB
    fc_kernel<<<dim3(16384), dim3(256), lds_fc, stream>>>(hs, fcW, fcb, out);

    softmax_kernel<<<dim3(8192), dim3(256), 0, stream>>>(out);
}

// Round 7
// 4012.947 us; speedup vs baseline: 1.3709x; 1.3709x over previous
//
#include <hip/hip_runtime.h>
#include <math.h>

#define TT 512
#define BB 64
#define DIN 256
#define HH 512
#define DOUT 256

// A tiles: A_HI / A_LO, each 16 rows (= batches) x 768 f16. No ballast rows.
#define RSU 388          // row stride in u32 (384 data + 4 pad, 16B-aligned rows)
#define RSH 776          // row stride in f16
#define PST 68           // p_l row stride in f32

// LDS layout (u32 units)
#define A_HI_OFF 0
#define A_LO_OFF 6208    // 16*388
#define P_OFF    12416   // 32 rows x PST = 2176  (rows = kh*16 + batch)
#define B_OFF    14592   // 64 biases (gate*16 + unit)
#define C_OFF    14656   // 256 cell states (batch*16 + unit)
#define HST_HI   14912   // 128 u32 (256 u16) h-hi stage
#define HST_LO   15040   // 128 u32 h-lo stage
#define SMEM_U32 15168
#define SMEM_BYTES (SMEM_U32*4)

#define FCS 516          // fc LDS stride

typedef _Float16 f16x8 __attribute__((ext_vector_type(8)));
typedef float    f32x4 __attribute__((ext_vector_type(4)));
typedef unsigned u32x4 __attribute__((ext_vector_type(4)));

union H16 { _Float16 f; unsigned short u; };
__device__ __forceinline__ unsigned short f16bits(_Float16 h) { H16 t; t.f = h; return t.u; }

// split x,y into f16 hi + scaled-lo (lo = (x-hi)*2048 stays in f16 normal range)
__device__ __forceinline__ void pack2(float x, float y, unsigned& hi, unsigned& lo) {
    _Float16 hx = (_Float16)x, hy = (_Float16)y;
    _Float16 lx = (_Float16)((x - (float)hx) * 2048.0f);
    _Float16 ly = (_Float16)((y - (float)hy) * 2048.0f);
    hi = (unsigned)f16bits(hx) | ((unsigned)f16bits(hy) << 16);
    lo = (unsigned)f16bits(lx) | ((unsigned)f16bits(ly) << 16);
}

// coherent (LLC) 16B load/store — the ONLY exchange path (sc0-only proven
// unsafe in R3-R5: stale L1/L2 hits tag-false-match at period 4).
__device__ __forceinline__ u32x4 ld16_cohere(const void* p) {
    u32x4 v;
    asm volatile("global_load_dwordx4 %0, %1, off sc0 sc1"
                 : "=&v"(v) : "v"(p) : "memory");
    return v;
}
__device__ __forceinline__ void st16_cohere(void* p, u32x4 v) {
    asm volatile("global_store_dwordx4 %0, %1, off sc0 sc1"
                 :: "v"(p), "v"(v) : "memory");
}

// tag check: every u16 LSB of the 16B vector must equal `par`.
__device__ __forceinline__ bool tag_ok(u32x4 v, unsigned par) {
    unsigned a = v[0] & v[1] & v[2] & v[3];
    unsigned o = v[0] | v[1] | v[2] | v[3];
    unsigned x = par ? ~a : o;
    return (x & 0x00010001u) == 0u;
}

// ---------------- W fragments: fp32 global -> f16 hi/lo REGISTERS ----------------
// Wave (ct,kh): ONE 16-col subtile (gate ct), k-slices kh*12..+12.
// Lane (m,q): B-frag col = ct*16+m -> W row C = ct*HH + u0 + m.
// 12 x (hi,lo) f16x8 = 96 VGPR (R2-proven pressure level; no spills).
__device__ __forceinline__ void load_w_regs(const float* __restrict__ Whh,
                                            const float* __restrict__ Wih,
                                            int u0, int ct, int kh, int m, int q,
                                            f16x8 (&whi)[12], f16x8 (&wlo)[12]) {
    const int C = ct*HH + u0 + m;                  // gate-major row
    const float* rowH = Whh + (size_t)C*HH;
    const float* rowI = Wih + (size_t)C*DIN;
    #pragma unroll
    for (int j = 0; j < 12; ++j) {
        const int ks = kh*12 + j;                  // 0..23
        const float* src = (ks < 16) ? (rowH + ks*32 + q*8)
                                     : (rowI + (ks - 16)*32 + q*8);
        float4 a = ((const float4*)src)[0];
        float4 b = ((const float4*)src)[1];
        f16x8 h8, l8; _Float16 t16;
        t16=(_Float16)a.x; h8[0]=t16; l8[0]=(_Float16)((a.x-(float)t16)*2048.0f);
        t16=(_Float16)a.y; h8[1]=t16; l8[1]=(_Float16)((a.y-(float)t16)*2048.0f);
        t16=(_Float16)a.z; h8[2]=t16; l8[2]=(_Float16)((a.z-(float)t16)*2048.0f);
        t16=(_Float16)a.w; h8[3]=t16; l8[3]=(_Float16)((a.w-(float)t16)*2048.0f);
        t16=(_Float16)b.x; h8[4]=t16; l8[4]=(_Float16)((b.x-(float)t16)*2048.0f);
        t16=(_Float16)b.y; h8[5]=t16; l8[5]=(_Float16)((b.y-(float)t16)*2048.0f);
        t16=(_Float16)b.z; h8[6]=t16; l8[6]=(_Float16)((b.z-(float)t16)*2048.0f);
        t16=(_Float16)b.w; h8[7]=t16; l8[7]=(_Float16)((b.w-(float)t16)*2048.0f);
        whi[j] = h8; wlo[j] = l8;
    }
}

// ---------------- x staging: fp32 global -> A_HI/A_LO rows 0-15, k in [512,768) ----------------
__device__ __forceinline__ void stage_x_f16(unsigned* __restrict__ sm32,
                                            const float* __restrict__ src, int tid) {
    for (int r = 0; r < 2; ++r) {
        int idx4 = tid + 512*r;          // 1024 float4 = 16 rows x 64
        int b = idx4 >> 6, j4 = idx4 & 63;
        float4 v = ((const float4*)(src + (size_t)b*DIN))[j4];
        unsigned h0, l0, h1, l1;
        pack2(v.x, v.y, h0, l0);
        pack2(v.z, v.w, h1, l1);
        int o = b*RSU + 256 + 2*j4;
        sm32[A_HI_OFF + o]     = h0;
        sm32[A_HI_OFF + o + 1] = h1;
        sm32[A_LO_OFF + o]     = l0;
        sm32[A_LO_OFF + o + 1] = l1;
    }
}

__device__ __forceinline__ void stage_x_zero_f16(unsigned* __restrict__ sm32, int tid) {
    for (int r = 0; r < 2; ++r) {
        int idx = tid + 512*r;           // 1024: 16 rows x 64
        int row = idx >> 6, j = idx & 63;
        int o = row*RSU + 256 + 2*j;
        sm32[A_HI_OFF + o]     = 0u;
        sm32[A_HI_OFF + o + 1] = 0u;
        sm32[A_LO_OFF + o]     = 0u;
        sm32[A_LO_OFF + o + 1] = 0u;
    }
}

// ---------------- persistent LSTM kernel (Nb=64 geometry, 8 waves, pure-LLC exchange) ----------------
// Geometry: 4 batch-groups (g = blockIdx&3) x 16 batches; 32 producers/group
// (ij = blockIdx>>2) x 16 h-units. 128 blocks x 512 threads (2 waves/SIMD).
// Halves total LLC gather traffic vs Nb=32 (4 MB/step) with no MFMA ballast
// and R2-level register pressure (96-VGPR W file per wave).
// Exchange protocol identical to the R6-passing one: tag-in-data
// (LSB of every u16 = ((s+1)>>1)&1, slot=(s+1)&1), sc0sc1 publish + poll.
__global__ __launch_bounds__(512, 1)
void lstm_persist(const float* __restrict__ x, const float* __restrict__ target,
                  const float* __restrict__ h0, const float* __restrict__ c0,
                  const float* __restrict__ eWih, const float* __restrict__ eWhh,
                  const float* __restrict__ eb,
                  const float* __restrict__ dWih, const float* __restrict__ dWhh,
                  const float* __restrict__ db,
                  float* __restrict__ hs,
                  unsigned short* __restrict__ hbh,   // [2][64][512] f16-hi
                  unsigned short* __restrict__ hbl)   // [2][64][512] f16-lo
{
    extern __shared__ unsigned sm32[];
    float* p_l = (float*)(sm32 + P_OFF);
    float* b_l = (float*)(sm32 + B_OFF);
    float* c_l = (float*)(sm32 + C_OFF);
    unsigned* hst_hi = sm32 + HST_HI;
    unsigned* hst_lo = sm32 + HST_LO;

    const int tid = (int)threadIdx.x;
    const int g   = (int)(blockIdx.x & 3);     // batch group 0..3
    const int ij  = (int)(blockIdx.x >> 2);    // producer id 0..31
    const int b0  = g * 16;
    const int u0  = ij * 16;

    // ---- initial staging ----
    if (tid < 256) {
        int b = tid >> 4, u = tid & 15;
        c_l[tid] = c0[(size_t)(b0 + b)*HH + u0 + u];
    }
    if (tid < 64) b_l[tid] = eb[(tid >> 4)*HH + u0 + (tid & 15)];
    stage_x_f16(sm32, x + (size_t)b0*DIN, tid);     // x for s=0
    for (int r = 0; r < 4; ++r) {                    // h_{-1}=h0 -> A rows 0-15
        int idx4 = tid + 512*r;          // 2048 float4 = 16 rows x 128
        int b = idx4 >> 7, j4 = idx4 & 127;
        float4 v = ((const float4*)(h0 + (size_t)(b0 + b)*HH))[j4];
        unsigned h0p, l0p, h1p, l1p;
        pack2(v.x, v.y, h0p, l0p);
        pack2(v.z, v.w, h1p, l1p);
        int o = b*RSU + 2*j4;
        sm32[A_HI_OFF + o]     = h0p;
        sm32[A_HI_OFF + o + 1] = h1p;
        sm32[A_LO_OFF + o]     = l0p;
        sm32[A_LO_OFF + o + 1] = l1p;
    }
    __syncthreads();

    const int lane = tid & 63;
    const int wid  = tid >> 6;         // 0..7
    const int m    = lane & 15;        // A row sel / B col sel
    const int q    = lane >> 4;        // quad
    const int ct   = wid & 3;          // gate 0..3 (16-col subtile)
    const int kh   = wid >> 2;         // k-half (12 of 24 slices)

    const _Float16* aH = (const _Float16*)(sm32 + A_HI_OFF);
    const _Float16* aL = (const _Float16*)(sm32 + A_LO_OFF);
    const int abase = m*RSH + q*8 + (kh*12)*32;

    f16x8 whi[12], wlo[12];
    load_w_regs(eWhh, eWih, u0, ct, kh, m, q, whi, wlo);

    for (int s = 0; s < 1024; ++s) {
        // ---- 1. MFMA GEMM: C[16 batches x 16 cols] per wave, 3 products ----
        f32x4 hh = {0.f,0.f,0.f,0.f}, hl = {0.f,0.f,0.f,0.f}, lh = {0.f,0.f,0.f,0.f};
        #pragma unroll
        for (int j = 0; j < 12; ++j) {
            f16x8 ah = *(const f16x8*)(aH + abase + j*32);
            f16x8 al = *(const f16x8*)(aL + abase + j*32);
            hh = __builtin_amdgcn_mfma_f32_16x16x32_f16(ah, whi[j], hh, 0, 0, 0);
            hl = __builtin_amdgcn_mfma_f32_16x16x32_f16(ah, wlo[j], hl, 0, 0, 0);
            lh = __builtin_amdgcn_mfma_f32_16x16x32_f16(al, whi[j], lh, 0, 0, 0);
        }
        {
            // D: col = lane&15 = m (gate-col), row = q*4+i (batch).
            // p_l[(kh*16 + batch)*PST + ct*16 + m] = partial gate sum.
            const float sc = 1.0f/2048.0f;
            float* pb = p_l + (kh*16 + q*4)*PST + ct*16 + m;
            #pragma unroll
            for (int i = 0; i < 4; ++i)
                pb[i*PST] = hh[i] + (hl[i] + lh[i])*sc;
        }
        __syncthreads();

        const unsigned par = (unsigned)(((s + 1) >> 1) & 1);   // step tag bit

        // ---- 2. elementwise LSTM update -> LDS h-stage (tagged split-f16) ----
        float hval = 0.f;
        if (tid < 256) {
            const int b = tid >> 4, u = tid & 15;
            const float* p0 = p_l + (size_t)b*PST;          // kh=0 slab
            const float* p1 = p_l + (size_t)(16 + b)*PST;   // kh=1 slab
            float gi = b_l[u]      + p0[u]      + p1[u];
            float gf = b_l[16 + u] + p0[16 + u] + p1[16 + u];
            float gg = b_l[32 + u] + p0[32 + u] + p1[32 + u];
            float go = b_l[48 + u] + p0[48 + u] + p1[48 + u];
            float ii = 1.f/(1.f + expf(-gi));
            float ff = 1.f/(1.f + expf(-gf));
            float g2 = tanhf(gg);
            float oo = 1.f/(1.f + expf(-go));
            float c  = ff*c_l[tid] + ii*g2;
            c_l[tid] = c;
            hval = oo*tanhf(c);
            _Float16 hh16 = (_Float16)hval;
            unsigned uh = ((unsigned)f16bits(hh16) & 0xFFFEu) | par;
            H16 t16; t16.u = (unsigned short)uh;
            _Float16 hl16 = (_Float16)((hval - (float)t16.f) * 2048.0f);
            unsigned ul = ((unsigned)f16bits(hl16) & 0xFFFEu) | par;
            ((unsigned short*)hst_hi)[tid] = (unsigned short)uh;   // tid = b*16+u
            ((unsigned short*)hst_lo)[tid] = (unsigned short)ul;
        }
        __syncthreads();

        // ---- 3. publish: 64 coherent 16B stores (16 batches x 32B x hi/lo) ----
        if (tid < 64) {
            // order prior-step publishes before this one (waits on ~1-step-old
            // traffic only -> essentially free); guarantees period-4 tag safety.
            asm volatile("s_waitcnt vmcnt(0)" ::: "memory");
            const int b = tid >> 2, part = tid & 3;
            const int isLo = part >> 1, h16 = part & 1;
            u32x4 v = *(const u32x4*)((isLo ? hst_lo : hst_hi) + b*8 + h16*4);
            unsigned short* base = (isLo ? hbl : hbh)
                + ((size_t)((s & 1) ^ 1)*BB + b0 + b)*HH + u0 + h16*8;
            st16_cohere(base, v);
        }

        // ---- 4. off-critical-path tail ----
        if (s >= 512 && tid < 256) {
            int b = tid >> 4, u = tid & 15;
            hs[((size_t)(s - 512)*BB + (b0 + b))*HH + (u0 + u)] = hval;
        }
        if (s == 511) {
            load_w_regs(dWhh, dWih, u0, ct, kh, m, q, whi, wlo);   // decoder W
            if (tid < 64) b_l[tid] = db[(tid >> 4)*HH + u0 + (tid & 15)];
        }
        {
            int ns = s + 1;
            if (ns < 1024) {
                if (ns == 512)       stage_x_zero_f16(sm32, tid);
                else if (ns < 512)   stage_x_f16(sm32, x + ((size_t)ns*BB + b0)*DIN, tid);
                else                 stage_x_f16(sm32, target + ((size_t)(ns - 513)*BB + b0)*DOUT, tid);
            }
        }

        // ---- 5. gather h_s: poll the data itself (tag in every u16 LSB) ----
        if (s < 1023) {
            const int slot = (s + 1) & 1;
            const u32x4* SH = (const u32x4*)(hbh + (size_t)slot*BB*HH + (size_t)b0*HH);
            const u32x4* SL = (const u32x4*)(hbl + (size_t)slot*BB*HH + (size_t)b0*HH);
            u32x4 v0 = {0,0,0,0}, v1 = {0,0,0,0}, v2 = {0,0,0,0}, v3 = {0,0,0,0};
            unsigned pend = 0xFu;
            do {
                if (pend & 1u) v0 = ld16_cohere(SH + tid);
                if (pend & 2u) v1 = ld16_cohere(SH + tid + 512);
                if (pend & 4u) v2 = ld16_cohere(SL + tid);
                if (pend & 8u) v3 = ld16_cohere(SL + tid + 512);
                asm volatile("s_waitcnt vmcnt(0)"
                             : "+v"(v0), "+v"(v1), "+v"(v2), "+v"(v3) :: "memory");
                if (tag_ok(v0, par)) pend &= ~1u;
                if (tag_ok(v1, par)) pend &= ~2u;
                if (tag_ok(v2, par)) pend &= ~4u;
                if (tag_ok(v3, par)) pend &= ~8u;
            } while (pend);
            // scatter: hi -> A_HI, lo -> A_LO; 16 rows x 512 units (k<512)
            const int j = tid & 63, r0 = tid >> 6;
            *(u32x4*)(sm32 + A_HI_OFF + (r0    )*RSU + j*4) = v0;
            *(u32x4*)(sm32 + A_HI_OFF + (r0 + 8)*RSU + j*4) = v1;
            *(u32x4*)(sm32 + A_LO_OFF + (r0    )*RSU + j*4) = v2;
            *(u32x4*)(sm32 + A_LO_OFF + (r0 + 8)*RSU + j*4) = v3;
        }
        __syncthreads();   // A (h+x) visible before next MFMA
    }
}

// ---------------- FC (logits) kernel ----------------
__global__ __launch_bounds__(256, 1)
void fc_kernel(const float* __restrict__ hs, const float* __restrict__ W,
               const float* __restrict__ bias, float* __restrict__ out)
{
    extern __shared__ float sm[];
    float* hs_l = sm;              // 16 x FCS
    float* w_l  = sm + 16*FCS;     // 32 x FCS

    const int tid = (int)threadIdx.x;
    const int rb = (int)(blockIdx.x >> 3);
    const int cb = (int)(blockIdx.x & 7);

    for (int r = 0; r < 8; ++r) {
        int id = tid + 256*r;
        int b = id >> 7, j = id & 127;
        float4 v = ((const float4*)(hs + (size_t)(rb*16 + b)*HH))[j];
        *(float4*)(hs_l + b*FCS + 4*j) = v;
    }
    for (int r = 0; r < 16; ++r) {
        int id = tid + 256*r;
        int c = id >> 7, j = id & 127;
        float4 v = ((const float4*)(W + (size_t)(cb*32 + c)*HH))[j];
        *(float4*)(w_l + c*FCS + 4*j) = v;
    }
    __syncthreads();

    const int kc = tid & 7, bt = (tid >> 3) & 3, ct = tid >> 5;
    float acc[4][4] = {};
    const float* ap = hs_l + (bt*4)*FCS + 4*kc;
    const float* wp = w_l  + (ct*4)*FCS + 4*kc;
    #pragma unroll 4
    for (int i = 0; i < 16; ++i) {
        float4 av[4], wv[4];
        #pragma unroll
        for (int q = 0; q < 4; ++q) av[q] = *(const float4*)(ap + q*FCS + 32*i);
        #pragma unroll
        for (int q = 0; q < 4; ++q) wv[q] = *(const float4*)(wp + q*FCS + 32*i);
        #pragma unroll
        for (int b2 = 0; b2 < 4; ++b2)
            #pragma unroll
            for (int c2 = 0; c2 < 4; ++c2)
                acc[b2][c2] += av[b2].x*wv[c2].x + av[b2].y*wv[c2].y
                             + av[b2].z*wv[c2].z + av[b2].w*wv[c2].w;
    }
    #pragma unroll
    for (int b2 = 0; b2 < 4; ++b2)
        #pragma unroll
        for (int c2 = 0; c2 < 4; ++c2) {
            float v = acc[b2][c2];
            v += __shfl_xor(v, 1, 64);
            v += __shfl_xor(v, 2, 64);
            v += __shfl_xor(v, 4, 64);
            acc[b2][c2] = v;
        }
    if (kc == 0) {
        #pragma unroll
        for (int b2 = 0; b2 < 4; ++b2)
            #pragma unroll
            for (int c2 = 0; c2 < 4; ++c2) {
                int row = rb*16 + bt*4 + b2;
                int col = cb*32 + ct*4 + c2;
                out[(size_t)row*DOUT + col] = acc[b2][c2] + bias[col];
            }
    }
}

// ---------------- in-place softmax over last dim (256) ----------------
__global__ __launch_bounds__(256, 1)
void softmax_kernel(float* __restrict__ out)
{
    int row  = (int)blockIdx.x * 4 + ((int)threadIdx.x >> 6);
    int lane = (int)threadIdx.x & 63;
    float4 v = ((const float4*)(out + (size_t)row*DOUT))[lane];
    float m = fmaxf(fmaxf(v.x, v.y), fmaxf(v.z, v.w));
    #pragma unroll
    for (int d = 1; d < 64; d <<= 1) m = fmaxf(m, __shfl_xor(m, d, 64));
    float ex = expf(v.x - m), ey = expf(v.y - m), ez = expf(v.z - m), ew = expf(v.w - m);
    float ssum = ex + ey + ez + ew;
    #pragma unroll
    for (int d = 1; d < 64; d <<= 1) ssum += __shfl_xor(ssum, d, 64);
    float inv = 1.f / ssum;
    float4 o = make_float4(ex*inv, ey*inv, ez*inv, ew*inv);
    ((float4*)(out + (size_t)row*DOUT))[lane] = o;
}

// ---------------- exchange-buffer tag init (ws poisoned 0xAA before every call) ----------------
// slot0 first read at s=1 expects tag 1 -> init LSBs to 0.
// slot1 first read at s=0 expects tag 0 -> init LSBs to 1.
// sc0sc1 stores: init state lives at the LLC, where all polls go.
__global__ void init_kernel(unsigned* __restrict__ hbh32, unsigned* __restrict__ hbl32)
{
    int i = (int)blockIdx.x * 256 + (int)threadIdx.x;    // 0..16383
    unsigned* base = (i < 8192) ? hbh32 : hbl32;
    int j = (i & 8191) * 4;                              // u32 offset 0..32764
    unsigned val = (j < 16384) ? 0u : 0x00010001u;       // slot0 : slot1
    u32x4 v = {val, val, val, val};
    st16_cohere(base + j, v);
}

// ---------------- launch ----------------
extern "C" void kernel_launch(void* const* d_in, const int* in_sizes, int n_in,
                              void* d_out, int out_size, void* d_ws, size_t ws_size,
                              hipStream_t stream) {
    (void)in_sizes; (void)n_in; (void)out_size; (void)ws_size;
    const float* x      = (const float*)d_in[0];
    const float* target = (const float*)d_in[1];
    const float* h0     = (const float*)d_in[2];
    const float* c0     = (const float*)d_in[3];
    const float* eWih   = (const float*)d_in[4];
    const float* eWhh   = (const float*)d_in[5];
    const float* eb     = (const float*)d_in[6];
    const float* dWih   = (const float*)d_in[7];
    const float* dWhh   = (const float*)d_in[8];
    const float* db     = (const float*)d_in[9];
    const float* fcW    = (const float*)d_in[10];
    const float* fcb    = (const float*)d_in[11];
    float* out = (float*)d_out;

    float* hs = (float*)d_ws + 1024;                    // [T*B*H] decoder hidden
    unsigned short* hbh = (unsigned short*)(hs + (size_t)TT*BB*HH);  // [2][64][512] hi
    unsigned short* hbl = hbh + (size_t)2*BB*HH;                     // [2][64][512] lo

    init_kernel<<<dim3(64), dim3(256), 0, stream>>>((unsigned*)hbh, (unsigned*)hbl);

    lstm_persist<<<dim3(128), dim3(512), SMEM_BYTES, stream>>>(
        x, target, h0, c0, eWih, eWhh, eb, dWih, dWhh, db, hs, hbh, hbl);

    size_t lds_fc = (size_t)(48*FCS) * sizeof(float);   // ~99 KB
    fc_kernel<<<dim3(16384), dim3(256), lds_fc, stream>>>(hs, fcW, fcb, out);

    softmax_kernel<<<dim3(8192), dim3(256), 0, stream>>>(out);
}